// Round 3
// baseline (278.398 us; speedup 1.0000x reference)
//
#include <hip/hip_runtime.h>
#include <hip/hip_bf16.h>
#include <math.h>

typedef __attribute__((ext_vector_type(8))) short short8;
typedef __attribute__((ext_vector_type(4))) float f32x4;
typedef __attribute__((address_space(1))) const void CG;
typedef __attribute__((address_space(3))) void LS;

#define LOAD_LDS16(src, dst) __builtin_amdgcn_global_load_lds((CG*)(src), (LS*)(dst), 16, 0, 0)

__device__ __forceinline__ short f2bf(float f) {
  union { float f; unsigned u; } v; v.f = f;
  unsigned r = v.u + 0x7fffu + ((v.u >> 16) & 1u);
  return (short)(r >> 16);
}

// ---------------- fused transpose + fp32->bf16 for all 4 weights ----------------
__global__ __launch_bounds__(256) void transp_all(const float* __restrict__ w_qkv,
                                                  const float* __restrict__ w_out,
                                                  const float* __restrict__ w1,
                                                  const float* __restrict__ w2,
                                                  short* __restrict__ wqkvT,
                                                  short* __restrict__ woutT,
                                                  short* __restrict__ w1T,
                                                  short* __restrict__ w2T) {
  __shared__ short t[32][33];
  int bid = blockIdx.x;
  const float* W; short* Wt; int K, N, nx, id;
  if (bid < 1728)      { W = w_qkv; Wt = wqkvT; K = 768;  N = 2304; nx = 72; id = bid; }
  else if (bid < 2304) { W = w_out; Wt = woutT; K = 768;  N = 768;  nx = 24; id = bid - 1728; }
  else if (bid < 4608) { W = w1;    Wt = w1T;   K = 768;  N = 3072; nx = 96; id = bid - 2304; }
  else                 { W = w2;    Wt = w2T;   K = 3072; N = 768;  nx = 24; id = bid - 4608; }
  int n0 = (id % nx) << 5, k0 = (id / nx) << 5;
  int tid = threadIdx.x;
#pragma unroll
  for (int p = 0; p < 4; ++p) {
    int e = tid + (p << 8);
    int r = e >> 5, c = e & 31;
    t[r][c] = f2bf(W[(size_t)(k0 + r) * N + n0 + c]);
  }
  __syncthreads();
#pragma unroll
  for (int p = 0; p < 4; ++p) {
    int e = tid + (p << 8);
    int r = e >> 5, c = e & 31;
    Wt[(size_t)(n0 + r) * K + k0 + c] = t[c][r];
  }
}

// ---------------- LayerNorm (C=768), fp32 in -> bf16 out ----------------
__global__ __launch_bounds__(256) void ln_kernel(const float* __restrict__ x,
                                                 const float* __restrict__ g,
                                                 const float* __restrict__ b,
                                                 short* __restrict__ out) {
  int row = blockIdx.x;
  const float* xr = x + (size_t)row * 768;
  int tid = threadIdx.x;
  float v0 = xr[tid], v1 = xr[tid + 256], v2 = xr[tid + 512];
  float s = v0 + v1 + v2;
  float ss = v0 * v0 + v1 * v1 + v2 * v2;
#pragma unroll
  for (int m = 1; m < 64; m <<= 1) { s += __shfl_xor(s, m); ss += __shfl_xor(ss, m); }
  __shared__ float red[8];
  int w = tid >> 6;
  if ((tid & 63) == 0) { red[w] = s; red[w + 4] = ss; }
  __syncthreads();
  s = red[0] + red[1] + red[2] + red[3];
  ss = red[4] + red[5] + red[6] + red[7];
  float mean = s * (1.0f / 768.0f);
  float var = ss * (1.0f / 768.0f) - mean * mean;
  float rs = rsqrtf(var + 1e-5f);
  short* outr = out + (size_t)row * 768;
  outr[tid]       = f2bf((v0 - mean) * rs * g[tid]       + b[tid]);
  outr[tid + 256] = f2bf((v1 - mean) * rs * g[tid + 256] + b[tid + 256]);
  outr[tid + 512] = f2bf((v2 - mean) * rs * g[tid + 512] + b[tid + 512]);
}

// ---------------- GEMM: C[M,N] = A[M,K] @ Bt[N,K]^T  (bf16 in, fp32 acc) ----------------
// EPI 0: QKV split; 1: +resid->fp32; 2: +bias,GELU->bf16; 3: +bias+resid->fp32
// EPI 4: split-K (grid.z=2, lda=3072, K=1536): atomicAdd(out, c [+bias+resid if z==1])
template <int EPI>
__global__ __launch_bounds__(256, 2) void gemm_bt(
    const short* __restrict__ A, const short* __restrict__ Bt,
    int M, int N, int K,
    short* __restrict__ outQ, short* __restrict__ outK, short* __restrict__ outVt,
    float* __restrict__ outF, short* __restrict__ outB,
    const float* __restrict__ bias, const float* __restrict__ resid) {
  __shared__ short lA[128 * 32];
  __shared__ short lB[128 * 32];
  int tid = threadIdx.x;
  int lane = tid & 63, w = tid >> 6;
  int li = lane & 15, g = lane >> 4;
  int bm = blockIdx.y << 7, bn = blockIdx.x << 7;
  int wrow = (w >> 1) << 6, wcol = (w & 1) << 6;
  size_t lda = (EPI == 4) ? 3072 : (size_t)K;
  int koff = (EPI == 4) ? (int)blockIdx.z * 1536 : 0;

  const short* as[2];
  const short* bs[2];
#pragma unroll
  for (int p = 0; p < 2; ++p) {
    int v = tid + (p << 8);
    int row = v >> 2;
    int lc = (v & 3) ^ ((row ^ (row >> 2)) & 3);
    as[p] = A + (size_t)(bm + row) * lda + koff + lc * 8;
    bs[p] = Bt + (size_t)(bn + row) * lda + koff + lc * 8;
  }
  char* lAb = (char*)lA;
  char* lBb = (char*)lB;
  int sg = (g ^ ((li ^ (li >> 2)) & 3)) << 3;

  f32x4 zero = {0.f, 0.f, 0.f, 0.f};
  f32x4 acc[4][4];
#pragma unroll
  for (int i = 0; i < 4; ++i)
#pragma unroll
    for (int j = 0; j < 4; ++j) acc[i][j] = zero;

  for (int k0 = 0; k0 < K; k0 += 32) {
    __syncthreads();
#pragma unroll
    for (int p = 0; p < 2; ++p) {
      LOAD_LDS16(as[p] + k0, lAb + (p << 12) + (w << 10));
      LOAD_LDS16(bs[p] + k0, lBb + (p << 12) + (w << 10));
    }
    __syncthreads();
    short8 af[4], bf[4];
#pragma unroll
    for (int rt = 0; rt < 4; ++rt)
      af[rt] = *(const short8*)&lA[(wrow + rt * 16 + li) * 32 + sg];
#pragma unroll
    for (int ct = 0; ct < 4; ++ct)
      bf[ct] = *(const short8*)&lB[(wcol + ct * 16 + li) * 32 + sg];
#pragma unroll
    for (int rt = 0; rt < 4; ++rt)
#pragma unroll
      for (int ct = 0; ct < 4; ++ct)
        acc[rt][ct] = __builtin_amdgcn_mfma_f32_16x16x32_bf16(af[rt], bf[ct], acc[rt][ct], 0, 0, 0);
  }

#pragma unroll
  for (int rt = 0; rt < 4; ++rt) {
    int mbase = bm + wrow + rt * 16 + g * 4;
#pragma unroll
    for (int ct = 0; ct < 4; ++ct) {
      int n = bn + wcol + ct * 16 + li;
      f32x4 c = acc[rt][ct];
      if (EPI == 0) {
        if (n < 768) {
          int h = n >> 6, d = n & 63;
#pragma unroll
          for (int i = 0; i < 4; ++i) {
            int tok = mbase + i;
            int bb = tok >> 11, t = tok & 2047;
            outQ[((size_t)((bb * 12 + h) * 2048 + t) << 6) + d] = f2bf(c[i]);
          }
        } else if (n < 1536) {
          int nn = n - 768;
          int h = nn >> 6, d = nn & 63;
#pragma unroll
          for (int i = 0; i < 4; ++i) {
            int tok = mbase + i;
            int bb = tok >> 11, t = tok & 2047;
            outK[((size_t)((bb * 12 + h) * 2048 + t) << 6) + d] = f2bf(c[i]);
          }
        } else {
          int nn = n - 1536;
          int h = nn >> 6, d = nn & 63;
          int bb = mbase >> 11, t = mbase & 2047;
          ushort4 pk;
          pk.x = (unsigned short)f2bf(c[0]);
          pk.y = (unsigned short)f2bf(c[1]);
          pk.z = (unsigned short)f2bf(c[2]);
          pk.w = (unsigned short)f2bf(c[3]);
          *(ushort4*)((unsigned short*)outVt + (((size_t)((bb * 12 + h) * 64 + d)) << 11) + t) = pk;
        }
      } else if (EPI == 1) {
#pragma unroll
        for (int i = 0; i < 4; ++i) {
          int m = mbase + i;
          outF[(size_t)m * N + n] = c[i] + resid[(size_t)m * N + n];
        }
      } else if (EPI == 2) {
        float bv = bias[n];
#pragma unroll
        for (int i = 0; i < 4; ++i) {
          int m = mbase + i;
          float xx = c[i] + bv;
          float gel = 0.5f * xx * (1.0f + erff(xx * 0.70710678118654752f));
          outB[(size_t)m * N + n] = f2bf(gel);
        }
      } else if (EPI == 3) {
        float bv = bias[n];
#pragma unroll
        for (int i = 0; i < 4; ++i) {
          int m = mbase + i;
          outF[(size_t)m * N + n] = c[i] + bv + resid[(size_t)m * N + n];
        }
      } else {  // EPI 4: split-K atomic
        bool last = (blockIdx.z == 1);
        float bv = last ? bias[n] : 0.f;
#pragma unroll
        for (int i = 0; i < 4; ++i) {
          int m = mbase + i;
          float add = c[i] + bv + (last ? resid[(size_t)m * N + n] : 0.f);
          atomicAdd(&outF[(size_t)m * N + n], add);
        }
      }
    }
  }
}

// ---------------- causal flash attention v3 ----------------
// grid (64 qtiles of 32 rows, 24 bh), 256 threads = 4 waves.
// The 4 waves split the tile's key range into quarters (<=8 KV64 tiles each),
// K/V fragments read direct from global (L2/L3-resident), partial (m,l,o)
// merged via LDS tree at the end. No barriers in the main loop.
__global__ __launch_bounds__(256, 3) void attn_kernel(const short* __restrict__ Q,
                                                      const short* __restrict__ Kk,
                                                      const short* __restrict__ Vt,
                                                      short* __restrict__ O) {
  __shared__ short lP[4][32 * 64];     // per-wave P, chunk^=(row&7) swizzle
  __shared__ float cO[2][32][68];      // combine slots (padded)
  __shared__ float cL[2][32];
  __shared__ float cM[2][2];
  int tid = threadIdx.x;
  int lane = tid & 63, w = tid >> 6;
  int li = lane & 15, g = lane >> 4;
  int bh = blockIdx.y;
  int qi = 63 - (int)blockIdx.x;       // heavy tiles first
  int qbase = qi << 5;
  const short* Qb = Q + ((size_t)bh << 17);
  const short* Kb = Kk + ((size_t)bh << 17);
  const short* Vb = Vt + ((size_t)bh << 17);

  short8 qf[2][2];
#pragma unroll
  for (int rt = 0; rt < 2; ++rt)
#pragma unroll
    for (int kc = 0; kc < 2; ++kc)
      qf[rt][kc] = *(const short8*)&Qb[(size_t)(qbase + rt * 16 + li) * 64 + kc * 32 + g * 8];

  const short8 kOnes = {0x3F80, 0x3F80, 0x3F80, 0x3F80, 0x3F80, 0x3F80, 0x3F80, 0x3F80};
  f32x4 zero = {0.f, 0.f, 0.f, 0.f};
  f32x4 o[2][4];
  f32x4 lrow[2];
  float mrow[2] = {-1e30f, -1e30f};
#pragma unroll
  for (int rt = 0; rt < 2; ++rt) {
    lrow[rt] = zero;
#pragma unroll
    for (int ct = 0; ct < 4; ++ct) o[rt][ct] = zero;
  }

  int nkt = (qi >> 1) + 1;
  int cs = (nkt + 3) >> 2;
  int kbeg = w * cs;
  int kend = kbeg + cs; if (kend > nkt) kend = nkt;
  const float SCALE = 0.18033688011112042f;  // log2(e)/8
  int sw = li & 7;
  unsigned short* Pw = (unsigned short*)lP[w];

  for (int kt = kbeg; kt < kend; ++kt) {
    // ---- QK^T: S[32 q][64 k], K frags direct from global ----
    f32x4 s[2][4];
#pragma unroll
    for (int rt = 0; rt < 2; ++rt)
#pragma unroll
      for (int ct = 0; ct < 4; ++ct) s[rt][ct] = zero;
#pragma unroll
    for (int kc = 0; kc < 2; ++kc)
#pragma unroll
      for (int ct = 0; ct < 4; ++ct) {
        short8 kf = *(const short8*)&Kb[(size_t)(kt * 64 + ct * 16 + li) * 64 + kc * 32 + g * 8];
#pragma unroll
        for (int rt = 0; rt < 2; ++rt)
          s[rt][ct] = __builtin_amdgcn_mfma_f32_16x16x32_bf16(qf[rt][kc], kf, s[rt][ct], 0, 0, 0);
      }

    // ---- causal mask (only the last tile can cross the diagonal) ----
    if (kt == nkt - 1) {
      int kb0 = kt << 6;
#pragma unroll
      for (int rt = 0; rt < 2; ++rt) {
        int qrow0 = qbase + rt * 16 + g * 4;
#pragma unroll
        for (int ct = 0; ct < 4; ++ct) {
          int kcol = kb0 + ct * 16 + li;
#pragma unroll
          for (int i = 0; i < 4; ++i)
            if (kcol > qrow0 + i) s[rt][ct][i] = -1e30f;
        }
      }
    }

    // ---- per-16-row-group max, defer-rescale, P -> per-wave LDS ----
#pragma unroll
    for (int rt = 0; rt < 2; ++rt) {
      float tm = s[rt][0][0];
#pragma unroll
      for (int ct = 0; ct < 4; ++ct)
#pragma unroll
        for (int i = 0; i < 4; ++i) tm = fmaxf(tm, s[rt][ct][i]);
#pragma unroll
      for (int m2 = 1; m2 < 64; m2 <<= 1) tm = fmaxf(tm, __shfl_xor(tm, m2));
      if (tm > mrow[rt] + 8.0f) {  // wave-uniform
        float corr = exp2f((mrow[rt] - tm) * SCALE);
        mrow[rt] = tm;
#pragma unroll
        for (int i = 0; i < 4; ++i) lrow[rt][i] *= corr;
#pragma unroll
        for (int ct = 0; ct < 4; ++ct)
#pragma unroll
          for (int i = 0; i < 4; ++i) o[rt][ct][i] *= corr;
      }
#pragma unroll
      for (int ct = 0; ct < 4; ++ct)
#pragma unroll
        for (int i = 0; i < 4; ++i) {
          float p = exp2f((s[rt][ct][i] - mrow[rt]) * SCALE);
          int row = rt * 16 + (g << 2) + i;
          int col = (ct << 4) + li;
          int ch = (col >> 3) ^ (row & 7);
          Pw[(row << 6) + (ch << 3) + (col & 7)] = (unsigned short)f2bf(p);
        }
    }

    // ---- PV + row-sum via ones-MFMA; V frags direct from global ----
    f32x4 psum[2];
    psum[0] = zero; psum[1] = zero;
#pragma unroll
    for (int kc = 0; kc < 2; ++kc) {
      short8 vf[4];
#pragma unroll
      for (int ct = 0; ct < 4; ++ct)
        vf[ct] = *(const short8*)&Vb[(size_t)(ct * 16 + li) * 2048 + kt * 64 + kc * 32 + g * 8];
#pragma unroll
      for (int rt = 0; rt < 2; ++rt) {
        short8 pf = *(const short8*)&lP[w][(rt * 16 + li) * 64 + ((((kc << 2) | g) ^ sw) << 3)];
#pragma unroll
        for (int ct = 0; ct < 4; ++ct)
          o[rt][ct] = __builtin_amdgcn_mfma_f32_16x16x32_bf16(pf, vf[ct], o[rt][ct], 0, 0, 0);
        psum[rt] = __builtin_amdgcn_mfma_f32_16x16x32_bf16(pf, kOnes, psum[rt], 0, 0, 0);
      }
    }
#pragma unroll
    for (int rt = 0; rt < 2; ++rt)
#pragma unroll
      for (int i = 0; i < 4; ++i) lrow[rt][i] += psum[rt][i];
  }

  // ---- cross-wave combine: waves 2,3 -> slots; 0,1 merge; 1 -> slot0; 0 merges ----
  __syncthreads();
  if (w >= 2) {
    int slot = w - 2;
#pragma unroll
    for (int rt = 0; rt < 2; ++rt) {
      if (lane == 0) cM[slot][rt] = mrow[rt];
#pragma unroll
      for (int i = 0; i < 4; ++i) {
        int row = rt * 16 + (g << 2) + i;
        if (li == 0) cL[slot][row] = lrow[rt][i];
#pragma unroll
        for (int ct = 0; ct < 4; ++ct) cO[slot][row][ct * 16 + li] = o[rt][ct][i];
      }
    }
  }
  __syncthreads();
  if (w < 2) {
    int slot = w;
#pragma unroll
    for (int rt = 0; rt < 2; ++rt) {
      float ms = cM[slot][rt];
      float m2 = fmaxf(mrow[rt], ms);
      float fu = exp2f((mrow[rt] - m2) * SCALE);
      float fs = exp2f((ms - m2) * SCALE);
      mrow[rt] = m2;
#pragma unroll
      for (int i = 0; i < 4; ++i) {
        int row = rt * 16 + (g << 2) + i;
        lrow[rt][i] = lrow[rt][i] * fu + cL[slot][row] * fs;
#pragma unroll
        for (int ct = 0; ct < 4; ++ct)
          o[rt][ct][i] = o[rt][ct][i] * fu + cO[slot][row][ct * 16 + li] * fs;
      }
    }
  }
  __syncthreads();
  if (w == 1) {
#pragma unroll
    for (int rt = 0; rt < 2; ++rt) {
      if (lane == 0) cM[0][rt] = mrow[rt];
#pragma unroll
      for (int i = 0; i < 4; ++i) {
        int row = rt * 16 + (g << 2) + i;
        if (li == 0) cL[0][row] = lrow[rt][i];
#pragma unroll
        for (int ct = 0; ct < 4; ++ct) cO[0][row][ct * 16 + li] = o[rt][ct][i];
      }
    }
  }
  __syncthreads();
  if (w == 0) {
    int b = bh / 12, h = bh % 12;
#pragma unroll
    for (int rt = 0; rt < 2; ++rt) {
      float ms = cM[0][rt];
      float m2 = fmaxf(mrow[rt], ms);
      float fu = exp2f((mrow[rt] - m2) * SCALE);
      float fs = exp2f((ms - m2) * SCALE);
#pragma unroll
      for (int i = 0; i < 4; ++i) {
        int row = rt * 16 + (g << 2) + i;
        float l2 = lrow[rt][i] * fu + cL[0][row] * fs;
        float inv = 1.0f / l2;
        int t = qbase + row;
        size_t base = ((size_t)(b * 2048 + t)) * 768 + h * 64;
#pragma unroll
        for (int ct = 0; ct < 4; ++ct) {
          float ov = o[rt][ct][i] * fu + cO[0][row][ct * 16 + li] * fs;
          O[base + ct * 16 + li] = f2bf(ov * inv);
        }
      }
    }
  }
}

// ---------------- launch ----------------
extern "C" void kernel_launch(void* const* d_in, const int* in_sizes, int n_in,
                              void* d_out, int out_size, void* d_ws, size_t ws_size,
                              hipStream_t stream) {
  const float* x     = (const float*)d_in[0];
  const float* w_qkv = (const float*)d_in[1];
  const float* w_out = (const float*)d_in[2];
  const float* ln1g  = (const float*)d_in[3];
  const float* ln1b  = (const float*)d_in[4];
  const float* ln2g  = (const float*)d_in[5];
  const float* ln2b  = (const float*)d_in[6];
  const float* w1    = (const float*)d_in[7];
  const float* b1    = (const float*)d_in[8];
  const float* w2    = (const float*)d_in[9];
  const float* b2    = (const float*)d_in[10];
  float* out = (float*)d_out;
  char* ws = (char*)d_ws;

  short* wqkvT = (short*)(ws + 0);         // 2304x768 bf16
  short* woutT = (short*)(ws + 3538944);   // 768x768
  short* w1T   = (short*)(ws + 4718592);   // 3072x768
  short* w2T   = (short*)(ws + 9437184);   // 768x3072
  short* qb    = (short*)(ws + 14155776);  // [2,12,2048,64]
  short* kb    = (short*)(ws + 20447232);
  short* vtb   = (short*)(ws + 26738688);  // [2,12,64,2048]
  short* attnb = (short*)(ws + 33030144);  // [4096,768]
  short* ab    = qb;                        // FF1 out aliases q..attn
  short* xnb   = (short*)(ws + 39321600);  // LN out bf16 [4096,768]
  float* x2b   = (float*)(ws + 45613056);  // fp32 [4096,768]

  transp_all<<<dim3(6912), 256, 0, stream>>>(w_qkv, w_out, w1, w2, wqkvT, woutT, w1T, w2T);

  ln_kernel<<<dim3(4096), 256, 0, stream>>>(x, ln1g, ln1b, xnb);

  gemm_bt<0><<<dim3(18, 32), 256, 0, stream>>>(xnb, wqkvT, 4096, 2304, 768,
                                               qb, kb, vtb, nullptr, nullptr, nullptr, nullptr);

  attn_kernel<<<dim3(64, 24), 256, 0, stream>>>(qb, kb, vtb, attnb);

  gemm_bt<1><<<dim3(6, 32), 256, 0, stream>>>(attnb, woutT, 4096, 768, 768,
                                              nullptr, nullptr, nullptr, x2b, nullptr, nullptr, x);

  ln_kernel<<<dim3(4096), 256, 0, stream>>>(x2b, ln2g, ln2b, xnb);

  gemm_bt<2><<<dim3(24, 32), 256, 0, stream>>>(xnb, w1T, 4096, 3072, 768,
                                               nullptr, nullptr, nullptr, nullptr, ab, b1, nullptr);

  hipMemsetAsync(out, 0, (size_t)4096 * 768 * 4, stream);
  gemm_bt<4><<<dim3(6, 32, 2), 256, 0, stream>>>(ab, w2T, 4096, 768, 1536,
                                                 nullptr, nullptr, nullptr, out, nullptr, b2, x2b);
}

// Round 4
// 255.929 us; speedup vs baseline: 1.0878x; 1.0878x over previous
//
#include <hip/hip_runtime.h>
#include <hip/hip_bf16.h>
#include <math.h>

typedef __attribute__((ext_vector_type(8))) short short8;
typedef __attribute__((ext_vector_type(4))) float f32x4;
typedef __attribute__((address_space(1))) const void CG;
typedef __attribute__((address_space(3))) void LS;

#define LOAD_LDS16(src, dst) __builtin_amdgcn_global_load_lds((CG*)(src), (LS*)(dst), 16, 0, 0)

__device__ __forceinline__ short f2bf(float f) {
  union { float f; unsigned u; } v; v.f = f;
  unsigned r = v.u + 0x7fffu + ((v.u >> 16) & 1u);
  return (short)(r >> 16);
}

// ---------------- fused transpose + fp32->bf16 for all 4 weights ----------------
__global__ __launch_bounds__(256) void transp_all(const float* __restrict__ w_qkv,
                                                  const float* __restrict__ w_out,
                                                  const float* __restrict__ w1,
                                                  const float* __restrict__ w2,
                                                  short* __restrict__ wqkvT,
                                                  short* __restrict__ woutT,
                                                  short* __restrict__ w1T,
                                                  short* __restrict__ w2T) {
  __shared__ short t[32][33];
  int bid = blockIdx.x;
  const float* W; short* Wt; int K, N, nx, id;
  if (bid < 1728)      { W = w_qkv; Wt = wqkvT; K = 768;  N = 2304; nx = 72; id = bid; }
  else if (bid < 2304) { W = w_out; Wt = woutT; K = 768;  N = 768;  nx = 24; id = bid - 1728; }
  else if (bid < 4608) { W = w1;    Wt = w1T;   K = 768;  N = 3072; nx = 96; id = bid - 2304; }
  else                 { W = w2;    Wt = w2T;   K = 3072; N = 768;  nx = 24; id = bid - 4608; }
  int n0 = (id % nx) << 5, k0 = (id / nx) << 5;
  int tid = threadIdx.x;
#pragma unroll
  for (int p = 0; p < 4; ++p) {
    int e = tid + (p << 8);
    int r = e >> 5, c = e & 31;
    t[r][c] = f2bf(W[(size_t)(k0 + r) * N + n0 + c]);
  }
  __syncthreads();
#pragma unroll
  for (int p = 0; p < 4; ++p) {
    int e = tid + (p << 8);
    int r = e >> 5, c = e & 31;
    Wt[(size_t)(n0 + r) * K + k0 + c] = t[c][r];
  }
}

// ---------------- LayerNorm (C=768), fp32 in -> bf16 out ----------------
__global__ __launch_bounds__(256) void ln_kernel(const float* __restrict__ x,
                                                 const float* __restrict__ g,
                                                 const float* __restrict__ b,
                                                 short* __restrict__ out) {
  int row = blockIdx.x;
  const float* xr = x + (size_t)row * 768;
  int tid = threadIdx.x;
  float v0 = xr[tid], v1 = xr[tid + 256], v2 = xr[tid + 512];
  float s = v0 + v1 + v2;
  float ss = v0 * v0 + v1 * v1 + v2 * v2;
#pragma unroll
  for (int m = 1; m < 64; m <<= 1) { s += __shfl_xor(s, m); ss += __shfl_xor(ss, m); }
  __shared__ float red[8];
  int w = tid >> 6;
  if ((tid & 63) == 0) { red[w] = s; red[w + 4] = ss; }
  __syncthreads();
  s = red[0] + red[1] + red[2] + red[3];
  ss = red[4] + red[5] + red[6] + red[7];
  float mean = s * (1.0f / 768.0f);
  float var = ss * (1.0f / 768.0f) - mean * mean;
  float rs = rsqrtf(var + 1e-5f);
  short* outr = out + (size_t)row * 768;
  outr[tid]       = f2bf((v0 - mean) * rs * g[tid]       + b[tid]);
  outr[tid + 256] = f2bf((v1 - mean) * rs * g[tid + 256] + b[tid + 256]);
  outr[tid + 512] = f2bf((v2 - mean) * rs * g[tid + 512] + b[tid + 512]);
}

// ---------------- GEMM: C[M,N] = A[M,K] @ Bt[N,K]^T  (bf16 in, fp32 acc) ----------------
// EPI 0: QKV split; 1: +resid->fp32; 2: +bias,GELU->bf16; 3: +bias+resid->fp32
// EPI 4: split-K (grid.z=2, lda=3072, K=1536): atomicAdd(out, c [+bias+resid if z==1])
template <int EPI>
__global__ __launch_bounds__(256, 2) void gemm_bt(
    const short* __restrict__ A, const short* __restrict__ Bt,
    int M, int N, int K,
    short* __restrict__ outQ, short* __restrict__ outK, short* __restrict__ outVt,
    float* __restrict__ outF, short* __restrict__ outB,
    const float* __restrict__ bias, const float* __restrict__ resid) {
  __shared__ short lA[128 * 32];
  __shared__ short lB[128 * 32];
  int tid = threadIdx.x;
  int lane = tid & 63, w = tid >> 6;
  int li = lane & 15, g = lane >> 4;
  int bm = blockIdx.y << 7, bn = blockIdx.x << 7;
  int wrow = (w >> 1) << 6, wcol = (w & 1) << 6;
  size_t lda = (EPI == 4) ? 3072 : (size_t)K;
  int koff = (EPI == 4) ? (int)blockIdx.z * 1536 : 0;

  const short* as[2];
  const short* bs[2];
#pragma unroll
  for (int p = 0; p < 2; ++p) {
    int v = tid + (p << 8);
    int row = v >> 2;
    int lc = (v & 3) ^ ((row ^ (row >> 2)) & 3);
    as[p] = A + (size_t)(bm + row) * lda + koff + lc * 8;
    bs[p] = Bt + (size_t)(bn + row) * lda + koff + lc * 8;
  }
  char* lAb = (char*)lA;
  char* lBb = (char*)lB;
  int sg = (g ^ ((li ^ (li >> 2)) & 3)) << 3;

  f32x4 zero = {0.f, 0.f, 0.f, 0.f};
  f32x4 acc[4][4];
#pragma unroll
  for (int i = 0; i < 4; ++i)
#pragma unroll
    for (int j = 0; j < 4; ++j) acc[i][j] = zero;

  for (int k0 = 0; k0 < K; k0 += 32) {
    __syncthreads();
#pragma unroll
    for (int p = 0; p < 2; ++p) {
      LOAD_LDS16(as[p] + k0, lAb + (p << 12) + (w << 10));
      LOAD_LDS16(bs[p] + k0, lBb + (p << 12) + (w << 10));
    }
    __syncthreads();
    short8 af[4], bf[4];
#pragma unroll
    for (int rt = 0; rt < 4; ++rt)
      af[rt] = *(const short8*)&lA[(wrow + rt * 16 + li) * 32 + sg];
#pragma unroll
    for (int ct = 0; ct < 4; ++ct)
      bf[ct] = *(const short8*)&lB[(wcol + ct * 16 + li) * 32 + sg];
#pragma unroll
    for (int rt = 0; rt < 4; ++rt)
#pragma unroll
      for (int ct = 0; ct < 4; ++ct)
        acc[rt][ct] = __builtin_amdgcn_mfma_f32_16x16x32_bf16(af[rt], bf[ct], acc[rt][ct], 0, 0, 0);
  }

#pragma unroll
  for (int rt = 0; rt < 4; ++rt) {
    int mbase = bm + wrow + rt * 16 + g * 4;
#pragma unroll
    for (int ct = 0; ct < 4; ++ct) {
      int n = bn + wcol + ct * 16 + li;
      f32x4 c = acc[rt][ct];
      if (EPI == 0) {
        if (n < 768) {
          int h = n >> 6, d = n & 63;
#pragma unroll
          for (int i = 0; i < 4; ++i) {
            int tok = mbase + i;
            int bb = tok >> 11, t = tok & 2047;
            outQ[((size_t)((bb * 12 + h) * 2048 + t) << 6) + d] = f2bf(c[i]);
          }
        } else if (n < 1536) {
          int nn = n - 768;
          int h = nn >> 6, d = nn & 63;
#pragma unroll
          for (int i = 0; i < 4; ++i) {
            int tok = mbase + i;
            int bb = tok >> 11, t = tok & 2047;
            outK[((size_t)((bb * 12 + h) * 2048 + t) << 6) + d] = f2bf(c[i]);
          }
        } else {
          int nn = n - 1536;
          int h = nn >> 6, d = nn & 63;
          int bb = mbase >> 11, t = mbase & 2047;
          ushort4 pk;
          pk.x = (unsigned short)f2bf(c[0]);
          pk.y = (unsigned short)f2bf(c[1]);
          pk.z = (unsigned short)f2bf(c[2]);
          pk.w = (unsigned short)f2bf(c[3]);
          *(ushort4*)((unsigned short*)outVt + (((size_t)((bb * 12 + h) * 64 + d)) << 11) + t) = pk;
        }
      } else if (EPI == 1) {
#pragma unroll
        for (int i = 0; i < 4; ++i) {
          int m = mbase + i;
          outF[(size_t)m * N + n] = c[i] + resid[(size_t)m * N + n];
        }
      } else if (EPI == 2) {
        float bv = bias[n];
#pragma unroll
        for (int i = 0; i < 4; ++i) {
          int m = mbase + i;
          float xx = c[i] + bv;
          float gel = 0.5f * xx * (1.0f + erff(xx * 0.70710678118654752f));
          outB[(size_t)m * N + n] = f2bf(gel);
        }
      } else if (EPI == 3) {
        float bv = bias[n];
#pragma unroll
        for (int i = 0; i < 4; ++i) {
          int m = mbase + i;
          outF[(size_t)m * N + n] = c[i] + bv + resid[(size_t)m * N + n];
        }
      } else {  // EPI 4: split-K atomic
        bool last = (blockIdx.z == 1);
        float bv = last ? bias[n] : 0.f;
#pragma unroll
        for (int i = 0; i < 4; ++i) {
          int m = mbase + i;
          float add = c[i] + bv + (last ? resid[(size_t)m * N + n] : 0.f);
          atomicAdd(&outF[(size_t)m * N + n], add);
        }
      }
    }
  }
}

// ---------------- causal flash attention v4: block-level split-K ----------------
// grid (40 chunks, 24 bh). qtile qt (128 rows, 4 waves x 32) has 2(qt+1) KV64
// tiles split evenly into (qt>>2)+1 chunks (max chain 8). v2 inner loop:
// LDS-staged double-buffered K/V shared by 4 waves, defer-max, ones-MFMA rowsum.
// Partials (o bf16 col-major, m/l f32) to workspace; combine kernel merges.
__global__ __launch_bounds__(256, 3) void attn_kernel(const short* __restrict__ Q,
                                                      const short* __restrict__ Kk,
                                                      const short* __restrict__ Vt,
                                                      unsigned short* __restrict__ o_part,
                                                      float* __restrict__ ml_part) {
  __shared__ short lK[2][64 * 64];   // [key][dh], chunk^=(key&7) swizzle
  __shared__ short lV[2][64 * 64];   // [dh][key], chunk^=(dh&7)  swizzle
  __shared__ short lP[4][32 * 64];   // per-wave P, chunk^=(row&7) swizzle
  int tid = threadIdx.x;
  int lane = tid & 63, w = tid >> 6;
  int li = lane & 15, g = lane >> 4;
  int bh = blockIdx.y;
  int cid = 39 - (int)blockIdx.x;    // heavy chunks first
  // decode chunk -> (qt, c)
  int qt = 0, cum = 0;
  while (true) { int n = (qt >> 2) + 1; if (cid < cum + n) break; cum += n; ++qt; }
  int c = cid - cum;
  int nch = (qt >> 2) + 1;
  int nt = (qt + 1) << 1;
  int bq = nt / nch, rem = nt % nch;
  int t0 = c * bq + (c < rem ? c : rem);
  int t1 = t0 + bq + (c < rem ? 1 : 0);

  int qbase = (qt << 7) + (w << 5);
  const short* Qb = Q + ((size_t)bh << 17);
  const short* Kb = Kk + ((size_t)bh << 17);
  const short* Vb = Vt + ((size_t)bh << 17);

  short8 qf[2][2];
#pragma unroll
  for (int rt = 0; rt < 2; ++rt)
#pragma unroll
    for (int kc = 0; kc < 2; ++kc)
      qf[rt][kc] = *(const short8*)&Qb[(size_t)(qbase + rt * 16 + li) * 64 + kc * 32 + g * 8];

  int r0 = tid >> 3, s0 = (tid & 7) ^ (r0 & 7);
  int r1 = r0 + 32,  s1 = (tid & 7) ^ (r1 & 7);
  const short* kS0 = Kb + r0 * 64 + s0 * 8;
  const short* kS1 = Kb + r1 * 64 + s1 * 8;
  const short* vS0 = Vb + (size_t)r0 * 2048 + s0 * 8;
  const short* vS1 = Vb + (size_t)r1 * 2048 + s1 * 8;

#define STAGE(buf, kt)                                                        \
  do {                                                                        \
    LOAD_LDS16(kS0 + (size_t)(kt) * 4096, (char*)lK[buf] + (w << 10));        \
    LOAD_LDS16(kS1 + (size_t)(kt) * 4096, (char*)lK[buf] + 4096 + (w << 10)); \
    LOAD_LDS16(vS0 + (size_t)(kt) * 64,   (char*)lV[buf] + (w << 10));        \
    LOAD_LDS16(vS1 + (size_t)(kt) * 64,   (char*)lV[buf] + 4096 + (w << 10)); \
  } while (0)

  const short8 kOnes = {0x3F80, 0x3F80, 0x3F80, 0x3F80, 0x3F80, 0x3F80, 0x3F80, 0x3F80};
  f32x4 zero = {0.f, 0.f, 0.f, 0.f};
  f32x4 o[2][4];
  f32x4 lrow[2];
  float mrow[2] = {-1e30f, -1e30f};
#pragma unroll
  for (int rt = 0; rt < 2; ++rt) {
    lrow[rt] = zero;
#pragma unroll
    for (int ct = 0; ct < 4; ++ct) o[rt][ct] = zero;
  }

  int diagKt = qbase >> 6;
  const float SCALE = 0.18033688011112042f;  // log2(e)/8
  int sw = li & 7;
  unsigned short* Pw = (unsigned short*)lP[w];

  STAGE(0, t0);

  for (int kt = t0; kt < t1; ++kt) {
    int cur = (kt - t0) & 1;
    __syncthreads();                           // drains staged loads for buf[cur]
    if (kt + 1 < t1) STAGE(cur ^ 1, kt + 1);   // prefetch next (in flight to next barrier)

    if (kt <= diagKt) {
      const short* Kc = lK[cur];
      const short* Vc = lV[cur];

      f32x4 s[2][4];
#pragma unroll
      for (int rt = 0; rt < 2; ++rt)
#pragma unroll
        for (int ct = 0; ct < 4; ++ct) s[rt][ct] = zero;
#pragma unroll
      for (int kc = 0; kc < 2; ++kc)
#pragma unroll
        for (int ct = 0; ct < 4; ++ct) {
          short8 kf = *(const short8*)&Kc[(ct * 16 + li) * 64 + ((((kc << 2) | g) ^ sw) << 3)];
#pragma unroll
          for (int rt = 0; rt < 2; ++rt)
            s[rt][ct] = __builtin_amdgcn_mfma_f32_16x16x32_bf16(qf[rt][kc], kf, s[rt][ct], 0, 0, 0);
        }

      if (kt == diagKt) {
        int kb0 = kt << 6;
#pragma unroll
        for (int rt = 0; rt < 2; ++rt) {
          int qrow0 = qbase + rt * 16 + g * 4;
#pragma unroll
          for (int ct = 0; ct < 4; ++ct) {
            int kcol = kb0 + ct * 16 + li;
#pragma unroll
            for (int i = 0; i < 4; ++i)
              if (kcol > qrow0 + i) s[rt][ct][i] = -1e30f;
          }
        }
      }

#pragma unroll
      for (int rt = 0; rt < 2; ++rt) {
        float tm = s[rt][0][0];
#pragma unroll
        for (int ct = 0; ct < 4; ++ct)
#pragma unroll
          for (int i = 0; i < 4; ++i) tm = fmaxf(tm, s[rt][ct][i]);
#pragma unroll
        for (int m2 = 1; m2 < 64; m2 <<= 1) tm = fmaxf(tm, __shfl_xor(tm, m2));
        if (tm > mrow[rt] + 8.0f) {  // wave-uniform
          float corr = exp2f((mrow[rt] - tm) * SCALE);
          mrow[rt] = tm;
#pragma unroll
          for (int i = 0; i < 4; ++i) lrow[rt][i] *= corr;
#pragma unroll
          for (int ct = 0; ct < 4; ++ct)
#pragma unroll
            for (int i = 0; i < 4; ++i) o[rt][ct][i] *= corr;
        }
#pragma unroll
        for (int ct = 0; ct < 4; ++ct)
#pragma unroll
          for (int i = 0; i < 4; ++i) {
            float p = exp2f((s[rt][ct][i] - mrow[rt]) * SCALE);
            int row = rt * 16 + (g << 2) + i;
            int col = (ct << 4) + li;
            int ch = (col >> 3) ^ (row & 7);
            Pw[(row << 6) + (ch << 3) + (col & 7)] = (unsigned short)f2bf(p);
          }
      }

      f32x4 psum[2];
      psum[0] = zero; psum[1] = zero;
#pragma unroll
      for (int kc = 0; kc < 2; ++kc) {
        short8 vf[4];
#pragma unroll
        for (int ct = 0; ct < 4; ++ct)
          vf[ct] = *(const short8*)&Vc[(ct * 16 + li) * 64 + ((((kc << 2) | g) ^ sw) << 3)];
#pragma unroll
        for (int rt = 0; rt < 2; ++rt) {
          short8 pf = *(const short8*)&lP[w][(rt * 16 + li) * 64 + ((((kc << 2) | g) ^ sw) << 3)];
#pragma unroll
          for (int ct = 0; ct < 4; ++ct)
            o[rt][ct] = __builtin_amdgcn_mfma_f32_16x16x32_bf16(pf, vf[ct], o[rt][ct], 0, 0, 0);
          psum[rt] = __builtin_amdgcn_mfma_f32_16x16x32_bf16(pf, kOnes, psum[rt], 0, 0, 0);
        }
      }
#pragma unroll
      for (int rt = 0; rt < 2; ++rt)
#pragma unroll
        for (int i = 0; i < 4; ++i) lrow[rt][i] += psum[rt][i];
    }
  }
#undef STAGE

  // ---- write partials: o bf16 col-major [pid][64 col][128 row]; m/l f32 ----
  int pid = bh * 40 + cid;
#pragma unroll
  for (int rt = 0; rt < 2; ++rt)
#pragma unroll
    for (int ct = 0; ct < 4; ++ct) {
      int col = (ct << 4) + li;
      int row0 = (w << 5) + (rt << 4) + (g << 2);
      ushort4 pk;
      pk.x = (unsigned short)f2bf(o[rt][ct][0]);
      pk.y = (unsigned short)f2bf(o[rt][ct][1]);
      pk.z = (unsigned short)f2bf(o[rt][ct][2]);
      pk.w = (unsigned short)f2bf(o[rt][ct][3]);
      *(ushort4*)&o_part[((size_t)pid * 64 + col) * 128 + row0] = pk;
    }
  if (li == 0) {
    float2* mlp = (float2*)ml_part;
#pragma unroll
    for (int rt = 0; rt < 2; ++rt)
#pragma unroll
      for (int i = 0; i < 4; ++i) {
        int row = (w << 5) + (rt << 4) + (g << 2) + i;
        mlp[(size_t)pid * 128 + row] = make_float2(mrow[rt], lrow[rt][i]);
      }
  }
}

// ---------------- attention combine: merge <=4 chunks per (qt,bh) ----------------
__global__ __launch_bounds__(256) void attn_combine(const unsigned short* __restrict__ o_part,
                                                    const float* __restrict__ ml_part,
                                                    short* __restrict__ O) {
  __shared__ float wgt[4][128];
  int qt = blockIdx.x, bh = blockIdx.y;
  int a = qt >> 2, bb = qt & 3;
  int c0 = 2 * a * (a - 1) + a * bb + qt;   // cumulative chunks before qt
  int nch = a + 1;
  int pid0 = bh * 40 + c0;
  int tid = threadIdx.x;
  const float SCALE = 0.18033688011112042f;
  const float2* mlp = (const float2*)ml_part;

  if (tid < 128) {
    int row = tid;
    float mv[4] = {-1e30f, -1e30f, -1e30f, -1e30f};
    float lv[4] = {0.f, 0.f, 0.f, 0.f};
#pragma unroll
    for (int c = 0; c < 4; ++c)
      if (c < nch) {
        float2 ml = mlp[(size_t)(pid0 + c) * 128 + row];
        mv[c] = ml.x; lv[c] = ml.y;
      }
    float M = fmaxf(fmaxf(mv[0], mv[1]), fmaxf(mv[2], mv[3]));
    float u[4];
    float L = 0.f;
#pragma unroll
    for (int c = 0; c < 4; ++c) {
      u[c] = (c < nch) ? exp2f((mv[c] - M) * SCALE) : 0.f;
      L += lv[c] * u[c];
    }
    float inv = 1.0f / L;
#pragma unroll
    for (int c = 0; c < 4; ++c) wgt[c][row] = u[c] * inv;
  }
  __syncthreads();

  int col = tid & 63, rg = tid >> 6;
  int b = bh / 12, h = bh % 12;
  size_t obase[4];
#pragma unroll
  for (int c = 0; c < 4; ++c) obase[c] = ((size_t)(pid0 + c) * 64 + col) * 128;
  for (int r = 0; r < 32; ++r) {
    int row = (rg << 5) + r;
    float acc = 0.f;
#pragma unroll
    for (int c = 0; c < 4; ++c)
      if (c < nch) {
        union { unsigned u; float f; } cv;
        cv.u = ((unsigned)o_part[obase[c] + row]) << 16;
        acc += cv.f * wgt[c][row];
      }
    int t = (qt << 7) + row;
    O[((size_t)(b * 2048 + t)) * 768 + h * 64 + col] = f2bf(acc);
  }
}

// ---------------- launch ----------------
extern "C" void kernel_launch(void* const* d_in, const int* in_sizes, int n_in,
                              void* d_out, int out_size, void* d_ws, size_t ws_size,
                              hipStream_t stream) {
  const float* x     = (const float*)d_in[0];
  const float* w_qkv = (const float*)d_in[1];
  const float* w_out = (const float*)d_in[2];
  const float* ln1g  = (const float*)d_in[3];
  const float* ln1b  = (const float*)d_in[4];
  const float* ln2g  = (const float*)d_in[5];
  const float* ln2b  = (const float*)d_in[6];
  const float* w1    = (const float*)d_in[7];
  const float* b1    = (const float*)d_in[8];
  const float* w2    = (const float*)d_in[9];
  const float* b2    = (const float*)d_in[10];
  float* out = (float*)d_out;
  char* ws = (char*)d_ws;

  short* wqkvT = (short*)(ws + 0);         // 2304x768 bf16
  short* woutT = (short*)(ws + 3538944);   // 768x768
  short* w1T   = (short*)(ws + 4718592);   // 3072x768
  short* w2T   = (short*)(ws + 9437184);   // 768x3072
  short* qb    = (short*)(ws + 14155776);  // [2,12,2048,64]
  short* kb    = (short*)(ws + 20447232);
  short* vtb   = (short*)(ws + 26738688);  // [2,12,64,2048]
  short* attnb = (short*)(ws + 33030144);  // [4096,768]
  short* ab    = qb;                        // FF1 out aliases q..attn
  short* xnb   = (short*)(ws + 39321600);  // LN out bf16 [4096,768]
  float* x2b   = (float*)(ws + 45613056);  // fp32 [4096,768]
  // attn partials alias xnb+x2b (dead during attention):
  unsigned short* o_part = (unsigned short*)(ws + 39321600);  // 960x64x128 bf16 = 15.7MB
  float* ml_part = (float*)(ws + 55050240);                   // 960x128x2 f32 = 0.98MB (ends 56.03MB)

  transp_all<<<dim3(6912), 256, 0, stream>>>(w_qkv, w_out, w1, w2, wqkvT, woutT, w1T, w2T);

  ln_kernel<<<dim3(4096), 256, 0, stream>>>(x, ln1g, ln1b, xnb);

  gemm_bt<0><<<dim3(18, 32), 256, 0, stream>>>(xnb, wqkvT, 4096, 2304, 768,
                                               qb, kb, vtb, nullptr, nullptr, nullptr, nullptr);

  attn_kernel<<<dim3(40, 24), 256, 0, stream>>>(qb, kb, vtb, o_part, ml_part);
  attn_combine<<<dim3(16, 24), 256, 0, stream>>>(o_part, ml_part, attnb);

  gemm_bt<1><<<dim3(6, 32), 256, 0, stream>>>(attnb, woutT, 4096, 768, 768,
                                              nullptr, nullptr, nullptr, x2b, nullptr, nullptr, x);

  ln_kernel<<<dim3(4096), 256, 0, stream>>>(x2b, ln2g, ln2b, xnb);

  gemm_bt<2><<<dim3(24, 32), 256, 0, stream>>>(xnb, w1T, 4096, 3072, 768,
                                               nullptr, nullptr, nullptr, nullptr, ab, b1, nullptr);

  hipMemsetAsync(out, 0, (size_t)4096 * 768 * 4, stream);
  gemm_bt<4><<<dim3(6, 32, 2), 256, 0, stream>>>(ab, w2T, 4096, 768, 1536,
                                                 nullptr, nullptr, nullptr, out, nullptr, b2, x2b);
}

// Round 5
// 243.806 us; speedup vs baseline: 1.1419x; 1.0497x over previous
//
#include <hip/hip_runtime.h>
#include <hip/hip_bf16.h>
#include <math.h>

typedef __attribute__((ext_vector_type(8))) short short8;
typedef __attribute__((ext_vector_type(4))) float f32x4;
typedef __attribute__((address_space(1))) const void CG;
typedef __attribute__((address_space(3))) void LS;

#define LOAD_LDS16(src, dst) __builtin_amdgcn_global_load_lds((CG*)(src), (LS*)(dst), 16, 0, 0)

__device__ __forceinline__ short f2bf(float f) {
  union { float f; unsigned u; } v; v.f = f;
  unsigned r = v.u + 0x7fffu + ((v.u >> 16) & 1u);
  return (short)(r >> 16);
}

// ---------------- fused transpose + fp32->bf16 for all 4 weights ----------------
__global__ __launch_bounds__(256) void transp_all(const float* __restrict__ w_qkv,
                                                  const float* __restrict__ w_out,
                                                  const float* __restrict__ w1,
                                                  const float* __restrict__ w2,
                                                  short* __restrict__ wqkvT,
                                                  short* __restrict__ woutT,
                                                  short* __restrict__ w1T,
                                                  short* __restrict__ w2T) {
  __shared__ short t[32][33];
  int bid = blockIdx.x;
  const float* W; short* Wt; int K, N, nx, id;
  if (bid < 1728)      { W = w_qkv; Wt = wqkvT; K = 768;  N = 2304; nx = 72; id = bid; }
  else if (bid < 2304) { W = w_out; Wt = woutT; K = 768;  N = 768;  nx = 24; id = bid - 1728; }
  else if (bid < 4608) { W = w1;    Wt = w1T;   K = 768;  N = 3072; nx = 96; id = bid - 2304; }
  else                 { W = w2;    Wt = w2T;   K = 3072; N = 768;  nx = 24; id = bid - 4608; }
  int n0 = (id % nx) << 5, k0 = (id / nx) << 5;
  int tid = threadIdx.x;
#pragma unroll
  for (int p = 0; p < 4; ++p) {
    int e = tid + (p << 8);
    int r = e >> 5, c = e & 31;
    t[r][c] = f2bf(W[(size_t)(k0 + r) * N + n0 + c]);
  }
  __syncthreads();
#pragma unroll
  for (int p = 0; p < 4; ++p) {
    int e = tid + (p << 8);
    int r = e >> 5, c = e & 31;
    Wt[(size_t)(n0 + r) * K + k0 + c] = t[c][r];
  }
}

// ---------------- LayerNorm (C=768), fp32 in -> bf16 out ----------------
__global__ __launch_bounds__(256) void ln_kernel(const float* __restrict__ x,
                                                 const float* __restrict__ g,
                                                 const float* __restrict__ b,
                                                 short* __restrict__ out) {
  int row = blockIdx.x;
  const float* xr = x + (size_t)row * 768;
  int tid = threadIdx.x;
  float v0 = xr[tid], v1 = xr[tid + 256], v2 = xr[tid + 512];
  float s = v0 + v1 + v2;
  float ss = v0 * v0 + v1 * v1 + v2 * v2;
#pragma unroll
  for (int m = 1; m < 64; m <<= 1) { s += __shfl_xor(s, m); ss += __shfl_xor(ss, m); }
  __shared__ float red[8];
  int w = tid >> 6;
  if ((tid & 63) == 0) { red[w] = s; red[w + 4] = ss; }
  __syncthreads();
  s = red[0] + red[1] + red[2] + red[3];
  ss = red[4] + red[5] + red[6] + red[7];
  float mean = s * (1.0f / 768.0f);
  float var = ss * (1.0f / 768.0f) - mean * mean;
  float rs = rsqrtf(var + 1e-5f);
  short* outr = out + (size_t)row * 768;
  outr[tid]       = f2bf((v0 - mean) * rs * g[tid]       + b[tid]);
  outr[tid + 256] = f2bf((v1 - mean) * rs * g[tid + 256] + b[tid + 256]);
  outr[tid + 512] = f2bf((v2 - mean) * rs * g[tid + 512] + b[tid + 512]);
}

// ---------------- GEMM: C[M,N] = A[M,K] @ Bt[N,K]^T  (bf16 in, fp32 acc) ----------------
// Double-buffered prefetch K-loop (1 barrier/K-step, loads in flight across compute)
// + XCD-aware, GROUP_M=8 tile swizzle for L2 panel reuse.
// EPI 0: QKV split; 1: +resid->fp32; 2: +bias,GELU->bf16; 3: +bias+resid->fp32
// EPI 4: split-K (grid.z=2, lda=3072, K=1536): atomicAdd(out, c [+bias+resid if z==1])
template <int EPI>
__global__ __launch_bounds__(256, 2) void gemm_bt(
    const short* __restrict__ A, const short* __restrict__ Bt,
    int M, int N, int K,
    short* __restrict__ outQ, short* __restrict__ outK, short* __restrict__ outVt,
    float* __restrict__ outF, short* __restrict__ outB,
    const float* __restrict__ bias, const float* __restrict__ resid) {
  __shared__ short lA[2][128 * 32];
  __shared__ short lB[2][128 * 32];
  int tid = threadIdx.x;
  int lane = tid & 63, w = tid >> 6;
  int li = lane & 15, g = lane >> 4;

  // --- XCD chunk + GROUP_M=8 tile order (all grids have nwg % 8 == 0) ---
  int nx = gridDim.x, ny = gridDim.y;
  int nwg = nx * ny;
  int fid = (int)blockIdx.y * nx + (int)blockIdx.x;
  int nid = (fid & 7) * (nwg >> 3) + (fid >> 3);
  const int GM = 8;
  int npg = GM * nx;
  int grp = nid / npg;
  int fm = grp * GM;
  int gs = min(GM, ny - fm);
  int lid = nid - grp * npg;
  int bm = (fm + lid % gs) << 7;
  int bn = (lid / gs) << 7;

  int wrow = (w >> 1) << 6, wcol = (w & 1) << 6;
  size_t lda = (EPI == 4) ? 3072 : (size_t)K;
  int koff = (EPI == 4) ? (int)blockIdx.z * 1536 : 0;

  const short* as[2];
  const short* bs[2];
#pragma unroll
  for (int p = 0; p < 2; ++p) {
    int v = tid + (p << 8);
    int row = v >> 2;
    int lc = (v & 3) ^ ((row ^ (row >> 2)) & 3);
    as[p] = A + (size_t)(bm + row) * lda + koff + lc * 8;
    bs[p] = Bt + (size_t)(bn + row) * lda + koff + lc * 8;
  }
  int sg = (g ^ ((li ^ (li >> 2)) & 3)) << 3;

  f32x4 zero = {0.f, 0.f, 0.f, 0.f};
  f32x4 acc[4][4];
#pragma unroll
  for (int i = 0; i < 4; ++i)
#pragma unroll
    for (int j = 0; j < 4; ++j) acc[i][j] = zero;

#define GSTAGE(buf, ki)                                                 \
  do {                                                                  \
    int kk = (ki) << 5;                                                 \
    LOAD_LDS16(as[0] + kk, (char*)lA[buf] + (w << 10));                 \
    LOAD_LDS16(as[1] + kk, (char*)lA[buf] + 4096 + (w << 10));          \
    LOAD_LDS16(bs[0] + kk, (char*)lB[buf] + (w << 10));                 \
    LOAD_LDS16(bs[1] + kk, (char*)lB[buf] + 4096 + (w << 10));          \
  } while (0)

  int nk = K >> 5;
  GSTAGE(0, 0);
  for (int ki = 0; ki < nk; ++ki) {
    int cur = ki & 1;
    __syncthreads();                          // drains buf[cur] loads
    if (ki + 1 < nk) GSTAGE(cur ^ 1, ki + 1); // prefetch next (in flight to next barrier)
    const short* lAc = lA[cur];
    const short* lBc = lB[cur];
    short8 af[4], bf[4];
#pragma unroll
    for (int rt = 0; rt < 4; ++rt)
      af[rt] = *(const short8*)&lAc[(wrow + rt * 16 + li) * 32 + sg];
#pragma unroll
    for (int ct = 0; ct < 4; ++ct)
      bf[ct] = *(const short8*)&lBc[(wcol + ct * 16 + li) * 32 + sg];
#pragma unroll
    for (int rt = 0; rt < 4; ++rt)
#pragma unroll
      for (int ct = 0; ct < 4; ++ct)
        acc[rt][ct] = __builtin_amdgcn_mfma_f32_16x16x32_bf16(af[rt], bf[ct], acc[rt][ct], 0, 0, 0);
  }
#undef GSTAGE

#pragma unroll
  for (int rt = 0; rt < 4; ++rt) {
    int mbase = bm + wrow + rt * 16 + g * 4;
#pragma unroll
    for (int ct = 0; ct < 4; ++ct) {
      int n = bn + wcol + ct * 16 + li;
      f32x4 c = acc[rt][ct];
      if (EPI == 0) {
        if (n < 768) {
          int h = n >> 6, d = n & 63;
#pragma unroll
          for (int i = 0; i < 4; ++i) {
            int tok = mbase + i;
            int bb = tok >> 11, t = tok & 2047;
            outQ[((size_t)((bb * 12 + h) * 2048 + t) << 6) + d] = f2bf(c[i]);
          }
        } else if (n < 1536) {
          int nn = n - 768;
          int h = nn >> 6, d = nn & 63;
#pragma unroll
          for (int i = 0; i < 4; ++i) {
            int tok = mbase + i;
            int bb = tok >> 11, t = tok & 2047;
            outK[((size_t)((bb * 12 + h) * 2048 + t) << 6) + d] = f2bf(c[i]);
          }
        } else {
          int nn = n - 1536;
          int h = nn >> 6, d = nn & 63;
          int bb = mbase >> 11, t = mbase & 2047;
          ushort4 pk;
          pk.x = (unsigned short)f2bf(c[0]);
          pk.y = (unsigned short)f2bf(c[1]);
          pk.z = (unsigned short)f2bf(c[2]);
          pk.w = (unsigned short)f2bf(c[3]);
          *(ushort4*)((unsigned short*)outVt + (((size_t)((bb * 12 + h) * 64 + d)) << 11) + t) = pk;
        }
      } else if (EPI == 1) {
#pragma unroll
        for (int i = 0; i < 4; ++i) {
          int m = mbase + i;
          outF[(size_t)m * N + n] = c[i] + resid[(size_t)m * N + n];
        }
      } else if (EPI == 2) {
        float bv = bias[n];
#pragma unroll
        for (int i = 0; i < 4; ++i) {
          int m = mbase + i;
          float xx = c[i] + bv;
          float gel = 0.5f * xx * (1.0f + erff(xx * 0.70710678118654752f));
          outB[(size_t)m * N + n] = f2bf(gel);
        }
      } else if (EPI == 3) {
        float bv = bias[n];
#pragma unroll
        for (int i = 0; i < 4; ++i) {
          int m = mbase + i;
          outF[(size_t)m * N + n] = c[i] + bv + resid[(size_t)m * N + n];
        }
      } else {  // EPI 4: split-K atomic
        bool last = (blockIdx.z == 1);
        float bv = last ? bias[n] : 0.f;
#pragma unroll
        for (int i = 0; i < 4; ++i) {
          int m = mbase + i;
          float add = c[i] + bv + (last ? resid[(size_t)m * N + n] : 0.f);
          atomicAdd(&outF[(size_t)m * N + n], add);
        }
      }
    }
  }
}

// ---------------- causal flash attention v4: block-level split-K ----------------
__global__ __launch_bounds__(256, 3) void attn_kernel(const short* __restrict__ Q,
                                                      const short* __restrict__ Kk,
                                                      const short* __restrict__ Vt,
                                                      unsigned short* __restrict__ o_part,
                                                      float* __restrict__ ml_part) {
  __shared__ short lK[2][64 * 64];   // [key][dh], chunk^=(key&7) swizzle
  __shared__ short lV[2][64 * 64];   // [dh][key], chunk^=(dh&7)  swizzle
  __shared__ short lP[4][32 * 64];   // per-wave P, chunk^=(row&7) swizzle
  int tid = threadIdx.x;
  int lane = tid & 63, w = tid >> 6;
  int li = lane & 15, g = lane >> 4;
  int bh = blockIdx.y;
  int cid = 39 - (int)blockIdx.x;    // heavy chunks first
  int qt = 0, cum = 0;
  while (true) { int n = (qt >> 2) + 1; if (cid < cum + n) break; cum += n; ++qt; }
  int c = cid - cum;
  int nch = (qt >> 2) + 1;
  int nt = (qt + 1) << 1;
  int bq = nt / nch, rem = nt % nch;
  int t0 = c * bq + (c < rem ? c : rem);
  int t1 = t0 + bq + (c < rem ? 1 : 0);

  int qbase = (qt << 7) + (w << 5);
  const short* Qb = Q + ((size_t)bh << 17);
  const short* Kb = Kk + ((size_t)bh << 17);
  const short* Vb = Vt + ((size_t)bh << 17);

  short8 qf[2][2];
#pragma unroll
  for (int rt = 0; rt < 2; ++rt)
#pragma unroll
    for (int kc = 0; kc < 2; ++kc)
      qf[rt][kc] = *(const short8*)&Qb[(size_t)(qbase + rt * 16 + li) * 64 + kc * 32 + g * 8];

  int r0 = tid >> 3, s0 = (tid & 7) ^ (r0 & 7);
  int r1 = r0 + 32,  s1 = (tid & 7) ^ (r1 & 7);
  const short* kS0 = Kb + r0 * 64 + s0 * 8;
  const short* kS1 = Kb + r1 * 64 + s1 * 8;
  const short* vS0 = Vb + (size_t)r0 * 2048 + s0 * 8;
  const short* vS1 = Vb + (size_t)r1 * 2048 + s1 * 8;

#define STAGE(buf, kt)                                                        \
  do {                                                                        \
    LOAD_LDS16(kS0 + (size_t)(kt) * 4096, (char*)lK[buf] + (w << 10));        \
    LOAD_LDS16(kS1 + (size_t)(kt) * 4096, (char*)lK[buf] + 4096 + (w << 10)); \
    LOAD_LDS16(vS0 + (size_t)(kt) * 64,   (char*)lV[buf] + (w << 10));        \
    LOAD_LDS16(vS1 + (size_t)(kt) * 64,   (char*)lV[buf] + 4096 + (w << 10)); \
  } while (0)

  const short8 kOnes = {0x3F80, 0x3F80, 0x3F80, 0x3F80, 0x3F80, 0x3F80, 0x3F80, 0x3F80};
  f32x4 zero = {0.f, 0.f, 0.f, 0.f};
  f32x4 o[2][4];
  f32x4 lrow[2];
  float mrow[2] = {-1e30f, -1e30f};
#pragma unroll
  for (int rt = 0; rt < 2; ++rt) {
    lrow[rt] = zero;
#pragma unroll
    for (int ct = 0; ct < 4; ++ct) o[rt][ct] = zero;
  }

  int diagKt = qbase >> 6;
  const float SCALE = 0.18033688011112042f;  // log2(e)/8
  int sw = li & 7;
  unsigned short* Pw = (unsigned short*)lP[w];

  STAGE(0, t0);

  for (int kt = t0; kt < t1; ++kt) {
    int cur = (kt - t0) & 1;
    __syncthreads();
    if (kt + 1 < t1) STAGE(cur ^ 1, kt + 1);

    if (kt <= diagKt) {
      const short* Kc = lK[cur];
      const short* Vc = lV[cur];

      f32x4 s[2][4];
#pragma unroll
      for (int rt = 0; rt < 2; ++rt)
#pragma unroll
        for (int ct = 0; ct < 4; ++ct) s[rt][ct] = zero;
#pragma unroll
      for (int kc = 0; kc < 2; ++kc)
#pragma unroll
        for (int ct = 0; ct < 4; ++ct) {
          short8 kf = *(const short8*)&Kc[(ct * 16 + li) * 64 + ((((kc << 2) | g) ^ sw) << 3)];
#pragma unroll
          for (int rt = 0; rt < 2; ++rt)
            s[rt][ct] = __builtin_amdgcn_mfma_f32_16x16x32_bf16(qf[rt][kc], kf, s[rt][ct], 0, 0, 0);
        }

      if (kt == diagKt) {
        int kb0 = kt << 6;
#pragma unroll
        for (int rt = 0; rt < 2; ++rt) {
          int qrow0 = qbase + rt * 16 + g * 4;
#pragma unroll
          for (int ct = 0; ct < 4; ++ct) {
            int kcol = kb0 + ct * 16 + li;
#pragma unroll
            for (int i = 0; i < 4; ++i)
              if (kcol > qrow0 + i) s[rt][ct][i] = -1e30f;
          }
        }
      }

#pragma unroll
      for (int rt = 0; rt < 2; ++rt) {
        float tm = s[rt][0][0];
#pragma unroll
        for (int ct = 0; ct < 4; ++ct)
#pragma unroll
          for (int i = 0; i < 4; ++i) tm = fmaxf(tm, s[rt][ct][i]);
#pragma unroll
        for (int m2 = 1; m2 < 64; m2 <<= 1) tm = fmaxf(tm, __shfl_xor(tm, m2));
        if (tm > mrow[rt] + 8.0f) {
          float corr = exp2f((mrow[rt] - tm) * SCALE);
          mrow[rt] = tm;
#pragma unroll
          for (int i = 0; i < 4; ++i) lrow[rt][i] *= corr;
#pragma unroll
          for (int ct = 0; ct < 4; ++ct)
#pragma unroll
            for (int i = 0; i < 4; ++i) o[rt][ct][i] *= corr;
        }
#pragma unroll
        for (int ct = 0; ct < 4; ++ct)
#pragma unroll
          for (int i = 0; i < 4; ++i) {
            float p = exp2f((s[rt][ct][i] - mrow[rt]) * SCALE);
            int row = rt * 16 + (g << 2) + i;
            int col = (ct << 4) + li;
            int ch = (col >> 3) ^ (row & 7);
            Pw[(row << 6) + (ch << 3) + (col & 7)] = (unsigned short)f2bf(p);
          }
      }

      f32x4 psum[2];
      psum[0] = zero; psum[1] = zero;
#pragma unroll
      for (int kc = 0; kc < 2; ++kc) {
        short8 vf[4];
#pragma unroll
        for (int ct = 0; ct < 4; ++ct)
          vf[ct] = *(const short8*)&Vc[(ct * 16 + li) * 64 + ((((kc << 2) | g) ^ sw) << 3)];
#pragma unroll
        for (int rt = 0; rt < 2; ++rt) {
          short8 pf = *(const short8*)&lP[w][(rt * 16 + li) * 64 + ((((kc << 2) | g) ^ sw) << 3)];
#pragma unroll
          for (int ct = 0; ct < 4; ++ct)
            o[rt][ct] = __builtin_amdgcn_mfma_f32_16x16x32_bf16(pf, vf[ct], o[rt][ct], 0, 0, 0);
          psum[rt] = __builtin_amdgcn_mfma_f32_16x16x32_bf16(pf, kOnes, psum[rt], 0, 0, 0);
        }
      }
#pragma unroll
      for (int rt = 0; rt < 2; ++rt)
#pragma unroll
        for (int i = 0; i < 4; ++i) lrow[rt][i] += psum[rt][i];
    }
  }
#undef STAGE

  int pid = bh * 40 + cid;
#pragma unroll
  for (int rt = 0; rt < 2; ++rt)
#pragma unroll
    for (int ct = 0; ct < 4; ++ct) {
      int col = (ct << 4) + li;
      int row0 = (w << 5) + (rt << 4) + (g << 2);
      ushort4 pk;
      pk.x = (unsigned short)f2bf(o[rt][ct][0]);
      pk.y = (unsigned short)f2bf(o[rt][ct][1]);
      pk.z = (unsigned short)f2bf(o[rt][ct][2]);
      pk.w = (unsigned short)f2bf(o[rt][ct][3]);
      *(ushort4*)&o_part[((size_t)pid * 64 + col) * 128 + row0] = pk;
    }
  if (li == 0) {
    float2* mlp = (float2*)ml_part;
#pragma unroll
    for (int rt = 0; rt < 2; ++rt)
#pragma unroll
      for (int i = 0; i < 4; ++i) {
        int row = (w << 5) + (rt << 4) + (g << 2) + i;
        mlp[(size_t)pid * 128 + row] = make_float2(mrow[rt], lrow[rt][i]);
      }
  }
}

// ---------------- attention combine: merge <=4 chunks per (qt,bh) ----------------
__global__ __launch_bounds__(256) void attn_combine(const unsigned short* __restrict__ o_part,
                                                    const float* __restrict__ ml_part,
                                                    short* __restrict__ O) {
  __shared__ float wgt[4][128];
  int qt = blockIdx.x, bh = blockIdx.y;
  int a = qt >> 2, bb = qt & 3;
  int c0 = 2 * a * (a - 1) + a * bb + qt;
  int nch = a + 1;
  int pid0 = bh * 40 + c0;
  int tid = threadIdx.x;
  const float SCALE = 0.18033688011112042f;
  const float2* mlp = (const float2*)ml_part;

  if (tid < 128) {
    int row = tid;
    float mv[4] = {-1e30f, -1e30f, -1e30f, -1e30f};
    float lv[4] = {0.f, 0.f, 0.f, 0.f};
#pragma unroll
    for (int c = 0; c < 4; ++c)
      if (c < nch) {
        float2 ml = mlp[(size_t)(pid0 + c) * 128 + row];
        mv[c] = ml.x; lv[c] = ml.y;
      }
    float M = fmaxf(fmaxf(mv[0], mv[1]), fmaxf(mv[2], mv[3]));
    float u[4];
    float L = 0.f;
#pragma unroll
    for (int c = 0; c < 4; ++c) {
      u[c] = (c < nch) ? exp2f((mv[c] - M) * SCALE) : 0.f;
      L += lv[c] * u[c];
    }
    float inv = 1.0f / L;
#pragma unroll
    for (int c = 0; c < 4; ++c) wgt[c][row] = u[c] * inv;
  }
  __syncthreads();

  int col = tid & 63, rg = tid >> 6;
  int b = bh / 12, h = bh % 12;
  size_t obase[4];
#pragma unroll
  for (int c = 0; c < 4; ++c) obase[c] = ((size_t)(pid0 + c) * 64 + col) * 128;
  for (int r = 0; r < 32; ++r) {
    int row = (rg << 5) + r;
    float acc = 0.f;
#pragma unroll
    for (int c = 0; c < 4; ++c)
      if (c < nch) {
        union { unsigned u; float f; } cv;
        cv.u = ((unsigned)o_part[obase[c] + row]) << 16;
        acc += cv.f * wgt[c][row];
      }
    int t = (qt << 7) + row;
    O[((size_t)(b * 2048 + t)) * 768 + h * 64 + col] = f2bf(acc);
  }
}

// ---------------- launch ----------------
extern "C" void kernel_launch(void* const* d_in, const int* in_sizes, int n_in,
                              void* d_out, int out_size, void* d_ws, size_t ws_size,
                              hipStream_t stream) {
  const float* x     = (const float*)d_in[0];
  const float* w_qkv = (const float*)d_in[1];
  const float* w_out = (const float*)d_in[2];
  const float* ln1g  = (const float*)d_in[3];
  const float* ln1b  = (const float*)d_in[4];
  const float* ln2g  = (const float*)d_in[5];
  const float* ln2b  = (const float*)d_in[6];
  const float* w1    = (const float*)d_in[7];
  const float* b1    = (const float*)d_in[8];
  const float* w2    = (const float*)d_in[9];
  const float* b2    = (const float*)d_in[10];
  float* out = (float*)d_out;
  char* ws = (char*)d_ws;

  short* wqkvT = (short*)(ws + 0);         // 2304x768 bf16
  short* woutT = (short*)(ws + 3538944);   // 768x768
  short* w1T   = (short*)(ws + 4718592);   // 3072x768
  short* w2T   = (short*)(ws + 9437184);   // 768x3072
  short* qb    = (short*)(ws + 14155776);  // [2,12,2048,64]
  short* kb    = (short*)(ws + 20447232);
  short* vtb   = (short*)(ws + 26738688);  // [2,12,64,2048]
  short* attnb = (short*)(ws + 33030144);  // [4096,768]
  short* ab    = qb;                        // FF1 out aliases q..attn
  short* xnb   = (short*)(ws + 39321600);  // LN out bf16 [4096,768]
  float* x2b   = (float*)(ws + 45613056);  // fp32 [4096,768]
  unsigned short* o_part = (unsigned short*)(ws + 39321600);  // aliases xnb/x2b (dead then)
  float* ml_part = (float*)(ws + 55050240);

  transp_all<<<dim3(6912), 256, 0, stream>>>(w_qkv, w_out, w1, w2, wqkvT, woutT, w1T, w2T);

  ln_kernel<<<dim3(4096), 256, 0, stream>>>(x, ln1g, ln1b, xnb);

  gemm_bt<0><<<dim3(18, 32), 256, 0, stream>>>(xnb, wqkvT, 4096, 2304, 768,
                                               qb, kb, vtb, nullptr, nullptr, nullptr, nullptr);

  attn_kernel<<<dim3(40, 24), 256, 0, stream>>>(qb, kb, vtb, o_part, ml_part);
  attn_combine<<<dim3(16, 24), 256, 0, stream>>>(o_part, ml_part, attnb);

  gemm_bt<1><<<dim3(6, 32), 256, 0, stream>>>(attnb, woutT, 4096, 768, 768,
                                              nullptr, nullptr, nullptr, x2b, nullptr, nullptr, x);

  ln_kernel<<<dim3(4096), 256, 0, stream>>>(x2b, ln2g, ln2b, xnb);

  gemm_bt<2><<<dim3(24, 32), 256, 0, stream>>>(xnb, w1T, 4096, 3072, 768,
                                               nullptr, nullptr, nullptr, nullptr, ab, b1, nullptr);

  hipMemsetAsync(out, 0, (size_t)4096 * 768 * 4, stream);
  gemm_bt<4><<<dim3(6, 32, 2), 256, 0, stream>>>(ab, w2T, 4096, 768, 1536,
                                                 nullptr, nullptr, nullptr, out, nullptr, b2, x2b);
}